// Round 1
// baseline (758.438 us; speedup 1.0000x reference)
//
#include <hip/hip_runtime.h>
#include <hip/hip_bf16.h>

#define VV 100000
#define EE 50
#define HH 64
#define BB 1024
#define TT 200
// 3H = 192

__device__ __forceinline__ float fsig(float x) {
    return 1.f / (1.f + __expf(-x));
}
__device__ __forceinline__ float ftanh(float x) {
    // 1 - 2/(e^{2x}+1): monotone-safe at +/-inf, no NaN
    float e = __expf(2.f * x);
    return 1.f - 2.f / (e + 1.f);
}

// ---------------- Kernel A: embW[v][c] = emb[v][:] @ Wx[:,c] + bi[c] ----------------
__global__ __launch_bounds__(256) void embw_kernel(
    const float* __restrict__ emb, const float* __restrict__ Wx,
    const float* __restrict__ bi, float* __restrict__ embW)
{
    __shared__ float wx_lds[EE * 192];
    __shared__ float emb_lds[32 * EE];
    const int tid = threadIdx.x;
    const int v0 = blockIdx.x * 32;
    for (int i = tid; i < EE * 192; i += 256) wx_lds[i] = Wx[i];
    for (int i = tid; i < 32 * EE; i += 256) emb_lds[i] = emb[(size_t)v0 * EE + i];
    __syncthreads();
    const int cg = tid & 63;   // column group: cols cg, cg+64, cg+128
    const int rg = tid >> 6;   // row group: rows rg*8 .. rg*8+7
    float acc[8][3];
    #pragma unroll
    for (int i = 0; i < 8; i++) {
        acc[i][0] = bi[cg];
        acc[i][1] = bi[cg + 64];
        acc[i][2] = bi[cg + 128];
    }
    for (int k = 0; k < EE; k++) {
        const float wx0 = wx_lds[k * 192 + cg];
        const float wx1 = wx_lds[k * 192 + cg + 64];
        const float wx2 = wx_lds[k * 192 + cg + 128];
        #pragma unroll
        for (int i = 0; i < 8; i++) {
            const float ev = emb_lds[(rg * 8 + i) * EE + k];
            acc[i][0] = fmaf(ev, wx0, acc[i][0]);
            acc[i][1] = fmaf(ev, wx1, acc[i][1]);
            acc[i][2] = fmaf(ev, wx2, acc[i][2]);
        }
    }
    #pragma unroll
    for (int i = 0; i < 8; i++) {
        const size_t row = (size_t)(v0 + rg * 8 + i) * 192;
        embW[row + cg]       = acc[i][0];
        embW[row + cg + 64]  = acc[i][1];
        embW[row + cg + 128] = acc[i][2];
    }
}

// ---------------- Kernel B: GRU recurrence (one direction per blockIdx.y) ----------------
// Block: 192 threads = 3 waves. Wave w owns gate columns [64w, 64w+64).
// R=4 batch rows per block; Wh column held in VGPRs; h state in LDS.
template<bool USE_EMBW>
__global__ __launch_bounds__(192) void gru_kernel(
    const int* __restrict__ ids,
    const float* __restrict__ embW_f, const float* __restrict__ embW_b,
    const float* __restrict__ emb,
    const float* __restrict__ Wx_f, const float* __restrict__ bi_f,
    const float* __restrict__ Wx_b, const float* __restrict__ bi_b,
    const float* __restrict__ Wh_f, const float* __restrict__ br_f,
    const float* __restrict__ Wh_b, const float* __restrict__ br_b,
    float* __restrict__ outb,     // [B, T, 128]
    float* __restrict__ hf_out)   // [B, 64] (forward final state)
{
    constexpr int R = 4;
    __shared__ float h_lds[R][64];
    __shared__ float rg_lds[R][64];
    __shared__ float hh_lds[R][64];
    __shared__ int ids_lds[R * TT];
    const int tid = threadIdx.x;
    const int w = tid >> 6;
    const int j = tid & 63;
    const int dir = blockIdx.y;
    const int b0 = blockIdx.x * R;
    const float* embW = dir ? embW_b : embW_f;
    const float* Wh   = dir ? Wh_b : Wh_f;
    const float* br   = dir ? br_b : br_f;
    const float* Wx   = dir ? Wx_b : Wx_f;
    const float* bi   = dir ? bi_b : bi_f;
    const int c = w * 64 + j;

    float whc[64];
    #pragma unroll
    for (int k = 0; k < 64; k++) whc[k] = Wh[k * 192 + c];
    const float brc = br[c];
    float wxc[EE];
    float bic = 0.f;
    if (!USE_EMBW) {
        #pragma unroll
        for (int k = 0; k < EE; k++) wxc[k] = Wx[k * 192 + c];
        bic = bi[c];
    }
    for (int i = tid; i < R * TT; i += 192) ids_lds[i] = ids[(size_t)b0 * TT + i];
    if (w == 0) {
        #pragma unroll
        for (int r = 0; r < R; r++) h_lds[r][j] = 0.f;
    }
    __syncthreads();

    for (int s = 0; s < TT; s++) {
        const int t = dir ? (TT - 1 - s) : s;
        int idv[R];
        float gxv[R], accv[R];
        #pragma unroll
        for (int r = 0; r < R; r++) idv[r] = ids_lds[r * TT + t];
        if (USE_EMBW) {
            #pragma unroll
            for (int r = 0; r < R; r++) gxv[r] = embW[(size_t)idv[r] * 192 + c];
        } else {
            #pragma unroll
            for (int r = 0; r < R; r++) {
                float acc = bic;
                const float* er = emb + (size_t)idv[r] * EE;
                #pragma unroll
                for (int k = 0; k < EE; k++) acc = fmaf(er[k], wxc[k], acc);
                gxv[r] = acc;
            }
        }
        #pragma unroll
        for (int r = 0; r < R; r++) {
            float acc = brc;
            const float4* h4 = (const float4*)(&h_lds[r][0]);
            #pragma unroll
            for (int k4 = 0; k4 < 16; k4++) {
                const float4 hv = h4[k4];
                acc = fmaf(hv.x, whc[4 * k4 + 0], acc);
                acc = fmaf(hv.y, whc[4 * k4 + 1], acc);
                acc = fmaf(hv.z, whc[4 * k4 + 2], acc);
                acc = fmaf(hv.w, whc[4 * k4 + 3], acc);
            }
            accv[r] = acc;
        }
        float zg[R] = {};
        if (w == 1) {
            #pragma unroll
            for (int r = 0; r < R; r++) rg_lds[r][j] = fsig(gxv[r] + accv[r]);
        } else if (w == 0) {
            #pragma unroll
            for (int r = 0; r < R; r++) zg[r] = fsig(gxv[r] + accv[r]);
        }
        __syncthreads();
        if (w == 2) {
            #pragma unroll
            for (int r = 0; r < R; r++)
                hh_lds[r][j] = ftanh(gxv[r] + rg_lds[r][j] * accv[r]);
        }
        __syncthreads();
        if (w == 0) {
            #pragma unroll
            for (int r = 0; r < R; r++) {
                const float hold = h_lds[r][j];
                float hnew = hold;
                if (idv[r] != 0) {
                    const float hh = hh_lds[r][j];
                    hnew = zg[r] * hold + (1.f - zg[r]) * hh;
                }
                h_lds[r][j] = hnew;
                outb[((size_t)(b0 + r) * TT + t) * 128 + dir * 64 + j] = hnew;
            }
        }
        __syncthreads();
    }
    if (dir == 0 && w == 0) {
        #pragma unroll
        for (int r = 0; r < R; r++) hf_out[(size_t)(b0 + r) * 64 + j] = h_lds[r][j];
    }
}

// ---------------- Kernel C: attention + context ----------------
__global__ __launch_bounds__(256) void attn_kernel(
    const int* __restrict__ ids,
    const float* __restrict__ outb,   // [B,T,128]
    const float* __restrict__ hf,     // [B,64]
    const float* __restrict__ Wk, const float* __restrict__ bk,
    const float* __restrict__ Wq, const float* __restrict__ bq,
    const float* __restrict__ We, const float* __restrict__ be,
    float* __restrict__ ctx)          // [B,128]
{
    __shared__ float wk_lds[128 * 64];
    __shared__ float q_lds[64];
    __shared__ float e_lds[TT];
    __shared__ float we_lds[64];
    __shared__ float ctx_red[128];
    const int b = blockIdx.x;
    const int tid = threadIdx.x;
    const int w = tid >> 6;
    const int j = tid & 63;
    for (int i = tid; i < 128 * 64; i += 256) wk_lds[i] = Wk[i];
    if (tid < 64) we_lds[tid] = We[tid];
    if (w == 1) {
        float acc = bq[j];
        for (int k = 0; k < 64; k++) acc = fmaf(hf[(size_t)b * 64 + k], Wq[k * 64 + j], acc);
        q_lds[j] = acc;
    }
    __syncthreads();
    const float bev = be[0];
    for (int t = w; t < TT; t += 4) {
        const float* orow = outb + ((size_t)b * TT + t) * 128;
        float acc = bk[j];
        #pragma unroll 4
        for (int i = 0; i < 128; i++) acc = fmaf(orow[i], wk_lds[i * 64 + j], acc);
        float e = ftanh(acc + q_lds[j]) * we_lds[j];
        #pragma unroll
        for (int off = 32; off > 0; off >>= 1) e += __shfl_down(e, off);
        if (j == 0) {
            float en = e + bev;
            if (ids[(size_t)b * TT + t] == 0) en -= 1e9f;
            e_lds[t] = en;
        }
    }
    __syncthreads();
    if (w == 0) {
        float m = -1e30f;
        for (int t = j; t < TT; t += 64) m = fmaxf(m, e_lds[t]);
        #pragma unroll
        for (int off = 32; off > 0; off >>= 1) m = fmaxf(m, __shfl_xor(m, off));
        float ssum = 0.f;
        for (int t = j; t < TT; t += 64) { const float v = __expf(e_lds[t] - m); e_lds[t] = v; ssum += v; }
        #pragma unroll
        for (int off = 32; off > 0; off >>= 1) ssum += __shfl_xor(ssum, off);
        const float inv = 1.f / ssum;
        for (int t = j; t < TT; t += 64) e_lds[t] *= inv;
    }
    __syncthreads();
    const int cc = tid & 127;
    const int half = tid >> 7;
    float acc = 0.f;
    for (int t = half * 100; t < half * 100 + 100; t++)
        acc = fmaf(e_lds[t], outb[((size_t)b * TT + t) * 128 + cc], acc);
    if (half == 1) ctx_red[cc] = acc;
    __syncthreads();
    if (half == 0) ctx[(size_t)b * 128 + cc] = acc + ctx_red[cc];
}

extern "C" void kernel_launch(void* const* d_in, const int* in_sizes, int n_in,
                              void* d_out, int out_size, void* d_ws, size_t ws_size,
                              hipStream_t stream) {
    const int*   ids  = (const int*)d_in[0];
    const float* emb  = (const float*)d_in[1];
    const float* Wx_f = (const float*)d_in[2];
    const float* Wh_f = (const float*)d_in[3];
    const float* bi_f = (const float*)d_in[4];
    const float* br_f = (const float*)d_in[5];
    const float* Wx_b = (const float*)d_in[6];
    const float* Wh_b = (const float*)d_in[7];
    const float* bi_b = (const float*)d_in[8];
    const float* br_b = (const float*)d_in[9];
    const float* Wk   = (const float*)d_in[10];
    const float* bk   = (const float*)d_in[11];
    const float* Wq   = (const float*)d_in[12];
    const float* bq   = (const float*)d_in[13];
    const float* We   = (const float*)d_in[14];
    const float* be   = (const float*)d_in[15];
    float* ctx = (float*)d_out;

    float* ws = (float*)d_ws;
    const size_t embw_elems = (size_t)VV * 192;
    const size_t out_elems  = (size_t)BB * TT * 128;
    const size_t hf_elems   = (size_t)BB * 64;
    const size_t need_embw  = (2 * embw_elems + out_elems + hf_elems) * sizeof(float);
    const bool use_embw = (ws_size >= need_embw);

    float *embW_f = nullptr, *embW_b = nullptr, *outb, *hf;
    if (use_embw) {
        embW_f = ws;
        embW_b = embW_f + embw_elems;
        outb   = embW_b + embw_elems;
        hf     = outb + out_elems;
    } else {
        outb = ws;
        hf   = outb + out_elems;
    }

    if (use_embw) {
        embw_kernel<<<VV / 32, 256, 0, stream>>>(emb, Wx_f, bi_f, embW_f);
        embw_kernel<<<VV / 32, 256, 0, stream>>>(emb, Wx_b, bi_b, embW_b);
        gru_kernel<true><<<dim3(BB / 4, 2), 192, 0, stream>>>(
            ids, embW_f, embW_b, emb, Wx_f, bi_f, Wx_b, bi_b,
            Wh_f, br_f, Wh_b, br_b, outb, hf);
    } else {
        gru_kernel<false><<<dim3(BB / 4, 2), 192, 0, stream>>>(
            ids, embW_f, embW_b, emb, Wx_f, bi_f, Wx_b, bi_b,
            Wh_f, br_f, Wh_b, br_b, outb, hf);
    }
    attn_kernel<<<BB, 256, 0, stream>>>(ids, outb, hf, Wk, bk, Wq, bq, We, be, ctx);
}

// Round 2
// 593.825 us; speedup vs baseline: 1.2772x; 1.2772x over previous
//
#include <hip/hip_runtime.h>
#include <hip/hip_bf16.h>

#define VV 100000
#define EE 50
#define HH 64
#define BB 1024
#define TT 200
// 3H = 192

__device__ __forceinline__ float fsig(float x) {
    return 1.f / (1.f + __expf(-x));
}
__device__ __forceinline__ float ftanh(float x) {
    float e = __expf(2.f * x);
    return 1.f - 2.f / (e + 1.f);
}

// ---------------- Kernel A: embW[v][c] = emb[v][:] @ Wx[:,c] + bi[c]  (both dirs via blockIdx.y) ----------------
__global__ __launch_bounds__(256) void embw_kernel(
    const float* __restrict__ emb,
    const float* __restrict__ Wx_f, const float* __restrict__ bi_f,
    const float* __restrict__ Wx_b, const float* __restrict__ bi_b,
    float* __restrict__ embW_f, float* __restrict__ embW_b)
{
    const float* Wx = blockIdx.y ? Wx_b : Wx_f;
    const float* bi = blockIdx.y ? bi_b : bi_f;
    float* embW     = blockIdx.y ? embW_b : embW_f;
    __shared__ float wx_lds[EE * 192];
    __shared__ float emb_lds[32 * EE];
    const int tid = threadIdx.x;
    const int v0 = blockIdx.x * 32;
    for (int i = tid; i < EE * 192; i += 256) wx_lds[i] = Wx[i];
    for (int i = tid; i < 32 * EE; i += 256) emb_lds[i] = emb[(size_t)v0 * EE + i];
    __syncthreads();
    const int cg = tid & 63;
    const int rg = tid >> 6;
    float acc[8][3];
    #pragma unroll
    for (int i = 0; i < 8; i++) {
        acc[i][0] = bi[cg];
        acc[i][1] = bi[cg + 64];
        acc[i][2] = bi[cg + 128];
    }
    for (int k = 0; k < EE; k++) {
        const float wx0 = wx_lds[k * 192 + cg];
        const float wx1 = wx_lds[k * 192 + cg + 64];
        const float wx2 = wx_lds[k * 192 + cg + 128];
        #pragma unroll
        for (int i = 0; i < 8; i++) {
            const float ev = emb_lds[(rg * 8 + i) * EE + k];
            acc[i][0] = fmaf(ev, wx0, acc[i][0]);
            acc[i][1] = fmaf(ev, wx1, acc[i][1]);
            acc[i][2] = fmaf(ev, wx2, acc[i][2]);
        }
    }
    #pragma unroll
    for (int i = 0; i < 8; i++) {
        const size_t row = (size_t)(v0 + rg * 8 + i) * 192;
        embW[row + cg]       = acc[i][0];
        embW[row + cg + 64]  = acc[i][1];
        embW[row + cg + 128] = acc[i][2];
    }
}

// ---------------- Kernel B v2: one wave per (sequence, direction); zero barriers in the step loop ----
// Lane j owns gate columns {j, 64+j, 128+j}; all 192 Wh weights in VGPRs.
// h broadcast via LDS float4 reads (single-wave workgroup: DS pipe in-order, no s_barrier needed).
// embW gather pipelined 2 steps ahead to hide L3/HBM latency.
__global__ __launch_bounds__(64, 2) void gru2_kernel(
    const int* __restrict__ ids,
    const float* __restrict__ embW_f, const float* __restrict__ embW_b,
    const float* __restrict__ Wh_f, const float* __restrict__ br_f,
    const float* __restrict__ Wh_b, const float* __restrict__ br_b,
    float* __restrict__ outb,     // [B, T, 128]
    float* __restrict__ hf_out)   // [B, 64]
{
    const int j   = threadIdx.x;
    const int b   = blockIdx.x;
    const int dir = blockIdx.y;
    const float* eW = dir ? embW_b : embW_f;
    const float* Wh = dir ? Wh_b : Wh_f;
    const float* br = dir ? br_b : br_f;

    float wz[64], wr[64], wn[64];
    #pragma unroll
    for (int k = 0; k < 64; k++) {
        wz[k] = Wh[k * 192 + j];
        wr[k] = Wh[k * 192 + 64 + j];
        wn[k] = Wh[k * 192 + 128 + j];
    }
    const float brz = br[j], brr = br[64 + j], brn = br[128 + j];

    __shared__ __align__(16) float h_lds[64];
    __shared__ int ids_lds[TT];
    for (int i = j; i < TT; i += 64) ids_lds[i] = ids[(size_t)b * TT + i];
    h_lds[j] = 0.f;
    float hj = 0.f;
    __syncthreads();   // one-time; none inside the step loop

    const int t0 = dir ? (TT - 1) : 0;
    const int dt = dir ? -1 : 1;

    int   id0 = ids_lds[t0];
    float gz0 = eW[(size_t)id0 * 192 + j];
    float gr0 = eW[(size_t)id0 * 192 + 64 + j];
    float gn0 = eW[(size_t)id0 * 192 + 128 + j];
    int   id1 = ids_lds[t0 + dt];
    float gz1 = eW[(size_t)id1 * 192 + j];
    float gr1 = eW[(size_t)id1 * 192 + 64 + j];
    float gn1 = eW[(size_t)id1 * 192 + 128 + j];

    float* obase = outb + (size_t)b * TT * 128 + dir * 64 + j;

    for (int s = 0; s < TT; s++) {
        const int t = t0 + s * dt;
        // prefetch step s+2
        int id2 = 0; float gz2 = 0.f, gr2 = 0.f, gn2 = 0.f;
        if (s + 2 < TT) {
            id2 = ids_lds[t + 2 * dt];
            gz2 = eW[(size_t)id2 * 192 + j];
            gr2 = eW[(size_t)id2 * 192 + 64 + j];
            gn2 = eW[(size_t)id2 * 192 + 128 + j];
        }
        // gh = h @ Wh + br  (three dots, 6 partial accumulators for dep-chain ILP)
        float az0 = brz, ar0 = brr, an0 = brn;
        float az1 = 0.f, ar1 = 0.f, an1 = 0.f;
        const float4* h4 = (const float4*)h_lds;
        #pragma unroll
        for (int k4 = 0; k4 < 16; k4++) {
            const float4 hv = h4[k4];
            az0 = fmaf(hv.x, wz[4 * k4 + 0], az0);
            ar0 = fmaf(hv.x, wr[4 * k4 + 0], ar0);
            an0 = fmaf(hv.x, wn[4 * k4 + 0], an0);
            az1 = fmaf(hv.y, wz[4 * k4 + 1], az1);
            ar1 = fmaf(hv.y, wr[4 * k4 + 1], ar1);
            an1 = fmaf(hv.y, wn[4 * k4 + 1], an1);
            az0 = fmaf(hv.z, wz[4 * k4 + 2], az0);
            ar0 = fmaf(hv.z, wr[4 * k4 + 2], ar0);
            an0 = fmaf(hv.z, wn[4 * k4 + 2], an0);
            az1 = fmaf(hv.w, wz[4 * k4 + 3], az1);
            ar1 = fmaf(hv.w, wr[4 * k4 + 3], ar1);
            an1 = fmaf(hv.w, wn[4 * k4 + 3], an1);
        }
        const float z  = fsig(gz0 + az0 + az1);
        const float r  = fsig(gr0 + ar0 + ar1);
        const float hh = ftanh(gn0 + r * (an0 + an1));
        float hnew = z * hj + (1.f - z) * hh;
        hnew = (id0 != 0) ? hnew : hj;
        hj = hnew;
        h_lds[j] = hj;               // in-order DS pipe: next iteration's reads observe this
        obase[(size_t)t * 128] = hj;
        id0 = id1; gz0 = gz1; gr0 = gr1; gn0 = gn1;
        id1 = id2; gz1 = gz2; gr1 = gr2; gn1 = gn2;
    }
    if (dir == 0) hf_out[(size_t)b * 64 + j] = hj;
}

// ---------------- (fallback) GRU 3-wave kernel, recompute-gx variant ----------------
template<bool USE_EMBW>
__global__ __launch_bounds__(192) void gru_kernel(
    const int* __restrict__ ids,
    const float* __restrict__ embW_f, const float* __restrict__ embW_b,
    const float* __restrict__ emb,
    const float* __restrict__ Wx_f, const float* __restrict__ bi_f,
    const float* __restrict__ Wx_b, const float* __restrict__ bi_b,
    const float* __restrict__ Wh_f, const float* __restrict__ br_f,
    const float* __restrict__ Wh_b, const float* __restrict__ br_b,
    float* __restrict__ outb, float* __restrict__ hf_out)
{
    constexpr int R = 4;
    __shared__ float h_lds[R][64];
    __shared__ float rg_lds[R][64];
    __shared__ float hh_lds[R][64];
    __shared__ int ids_lds[R * TT];
    const int tid = threadIdx.x;
    const int w = tid >> 6;
    const int j = tid & 63;
    const int dir = blockIdx.y;
    const int b0 = blockIdx.x * R;
    const float* embW = dir ? embW_b : embW_f;
    const float* Wh   = dir ? Wh_b : Wh_f;
    const float* br   = dir ? br_b : br_f;
    const float* Wx   = dir ? Wx_b : Wx_f;
    const float* bi   = dir ? bi_b : bi_f;
    const int c = w * 64 + j;

    float whc[64];
    #pragma unroll
    for (int k = 0; k < 64; k++) whc[k] = Wh[k * 192 + c];
    const float brc = br[c];
    float wxc[EE];
    float bic = 0.f;
    if (!USE_EMBW) {
        #pragma unroll
        for (int k = 0; k < EE; k++) wxc[k] = Wx[k * 192 + c];
        bic = bi[c];
    }
    for (int i = tid; i < R * TT; i += 192) ids_lds[i] = ids[(size_t)b0 * TT + i];
    if (w == 0) {
        #pragma unroll
        for (int r = 0; r < R; r++) h_lds[r][j] = 0.f;
    }
    __syncthreads();

    for (int s = 0; s < TT; s++) {
        const int t = dir ? (TT - 1 - s) : s;
        int idv[R];
        float gxv[R], accv[R];
        #pragma unroll
        for (int r = 0; r < R; r++) idv[r] = ids_lds[r * TT + t];
        if (USE_EMBW) {
            #pragma unroll
            for (int r = 0; r < R; r++) gxv[r] = embW[(size_t)idv[r] * 192 + c];
        } else {
            #pragma unroll
            for (int r = 0; r < R; r++) {
                float acc = bic;
                const float* er = emb + (size_t)idv[r] * EE;
                #pragma unroll
                for (int k = 0; k < EE; k++) acc = fmaf(er[k], wxc[k], acc);
                gxv[r] = acc;
            }
        }
        #pragma unroll
        for (int r = 0; r < R; r++) {
            float acc = brc;
            const float4* h4 = (const float4*)(&h_lds[r][0]);
            #pragma unroll
            for (int k4 = 0; k4 < 16; k4++) {
                const float4 hv = h4[k4];
                acc = fmaf(hv.x, whc[4 * k4 + 0], acc);
                acc = fmaf(hv.y, whc[4 * k4 + 1], acc);
                acc = fmaf(hv.z, whc[4 * k4 + 2], acc);
                acc = fmaf(hv.w, whc[4 * k4 + 3], acc);
            }
            accv[r] = acc;
        }
        float zg[R] = {};
        if (w == 1) {
            #pragma unroll
            for (int r = 0; r < R; r++) rg_lds[r][j] = fsig(gxv[r] + accv[r]);
        } else if (w == 0) {
            #pragma unroll
            for (int r = 0; r < R; r++) zg[r] = fsig(gxv[r] + accv[r]);
        }
        __syncthreads();
        if (w == 2) {
            #pragma unroll
            for (int r = 0; r < R; r++)
                hh_lds[r][j] = ftanh(gxv[r] + rg_lds[r][j] * accv[r]);
        }
        __syncthreads();
        if (w == 0) {
            #pragma unroll
            for (int r = 0; r < R; r++) {
                const float hold = h_lds[r][j];
                float hnew = hold;
                if (idv[r] != 0) {
                    const float hh = hh_lds[r][j];
                    hnew = zg[r] * hold + (1.f - zg[r]) * hh;
                }
                h_lds[r][j] = hnew;
                outb[((size_t)(b0 + r) * TT + t) * 128 + dir * 64 + j] = hnew;
            }
        }
        __syncthreads();
    }
    if (dir == 0 && w == 0) {
        #pragma unroll
        for (int r = 0; r < R; r++) hf_out[(size_t)(b0 + r) * 64 + j] = h_lds[r][j];
    }
}

// ---------------- Kernel C v2: attention with Wk columns in VGPRs ----------------
__global__ __launch_bounds__(256, 3) void attn2_kernel(
    const int* __restrict__ ids,
    const float* __restrict__ outb,   // [B,T,128]
    const float* __restrict__ hf,     // [B,64]
    const float* __restrict__ Wk, const float* __restrict__ bk,
    const float* __restrict__ Wq, const float* __restrict__ bq,
    const float* __restrict__ We, const float* __restrict__ be,
    float* __restrict__ ctx)          // [B,128]
{
    __shared__ float e_lds[TT];
    __shared__ float part[4][128];
    const int b = blockIdx.x;
    const int tid = threadIdx.x;
    const int w = tid >> 6;
    const int j = tid & 63;

    // Wk column j in registers (each wave holds its own copy)
    float wkc[128];
    #pragma unroll
    for (int i = 0; i < 128; i++) wkc[i] = Wk[i * 64 + j];

    // q_j computed redundantly per wave (no barrier needed)
    float qj = bq[j];
    {
        const float4* hf4 = (const float4*)(hf + (size_t)b * 64);
        #pragma unroll
        for (int k4 = 0; k4 < 16; k4++) {
            const float4 hv = hf4[k4];
            qj = fmaf(hv.x, Wq[(4 * k4 + 0) * 64 + j], qj);
            qj = fmaf(hv.y, Wq[(4 * k4 + 1) * 64 + j], qj);
            qj = fmaf(hv.z, Wq[(4 * k4 + 2) * 64 + j], qj);
            qj = fmaf(hv.w, Wq[(4 * k4 + 3) * 64 + j], qj);
        }
    }
    const float wej = We[j];
    const float bev = be[0];
    const float bkj = bk[j];

    for (int t = w; t < TT; t += 4) {
        const float4* o4 = (const float4*)(outb + ((size_t)b * TT + t) * 128);
        float a0 = bkj, a1 = qj;   // fold biases into the two partials
        #pragma unroll
        for (int i4 = 0; i4 < 32; i4++) {
            const float4 ov = o4[i4];
            a0 = fmaf(ov.x, wkc[4 * i4 + 0], a0);
            a1 = fmaf(ov.y, wkc[4 * i4 + 1], a1);
            a0 = fmaf(ov.z, wkc[4 * i4 + 2], a0);
            a1 = fmaf(ov.w, wkc[4 * i4 + 3], a1);
        }
        float v = ftanh(a0 + a1) * wej;
        #pragma unroll
        for (int off = 32; off > 0; off >>= 1) v += __shfl_xor(v, off);
        if (j == 0) {
            float en = v + bev;
            if (ids[(size_t)b * TT + t] == 0) en -= 1e9f;
            e_lds[t] = en;
        }
    }
    __syncthreads();
    if (w == 0) {
        float m = -1e30f;
        for (int t = j; t < TT; t += 64) m = fmaxf(m, e_lds[t]);
        #pragma unroll
        for (int off = 32; off > 0; off >>= 1) m = fmaxf(m, __shfl_xor(m, off));
        float ssum = 0.f;
        for (int t = j; t < TT; t += 64) { const float v = __expf(e_lds[t] - m); e_lds[t] = v; ssum += v; }
        #pragma unroll
        for (int off = 32; off > 0; off >>= 1) ssum += __shfl_xor(ssum, off);
        const float inv = 1.f / ssum;
        for (int t = j; t < TT; t += 64) e_lds[t] *= inv;
    }
    __syncthreads();
    // context: wave w covers t ≡ w (mod 4); lanes cover 128 cols in two halves
    float c0 = 0.f, c1 = 0.f;
    for (int t = w; t < TT; t += 4) {
        const float* orow = outb + ((size_t)b * TT + t) * 128;
        const float wt = e_lds[t];
        c0 = fmaf(wt, orow[j], c0);
        c1 = fmaf(wt, orow[64 + j], c1);
    }
    part[w][j] = c0;
    part[w][64 + j] = c1;
    __syncthreads();
    if (tid < 128)
        ctx[(size_t)b * 128 + tid] = part[0][tid] + part[1][tid] + part[2][tid] + part[3][tid];
}

extern "C" void kernel_launch(void* const* d_in, const int* in_sizes, int n_in,
                              void* d_out, int out_size, void* d_ws, size_t ws_size,
                              hipStream_t stream) {
    const int*   ids  = (const int*)d_in[0];
    const float* emb  = (const float*)d_in[1];
    const float* Wx_f = (const float*)d_in[2];
    const float* Wh_f = (const float*)d_in[3];
    const float* bi_f = (const float*)d_in[4];
    const float* br_f = (const float*)d_in[5];
    const float* Wx_b = (const float*)d_in[6];
    const float* Wh_b = (const float*)d_in[7];
    const float* bi_b = (const float*)d_in[8];
    const float* br_b = (const float*)d_in[9];
    const float* Wk   = (const float*)d_in[10];
    const float* bk   = (const float*)d_in[11];
    const float* Wq   = (const float*)d_in[12];
    const float* bq   = (const float*)d_in[13];
    const float* We   = (const float*)d_in[14];
    const float* be   = (const float*)d_in[15];
    float* ctx = (float*)d_out;

    float* ws = (float*)d_ws;
    const size_t embw_elems = (size_t)VV * 192;
    const size_t out_elems  = (size_t)BB * TT * 128;
    const size_t hf_elems   = (size_t)BB * 64;
    const size_t need_embw  = (2 * embw_elems + out_elems + hf_elems) * sizeof(float);
    const bool use_embw = (ws_size >= need_embw);

    float *embW_f = nullptr, *embW_b = nullptr, *outb, *hf;
    if (use_embw) {
        embW_f = ws;
        embW_b = embW_f + embw_elems;
        outb   = embW_b + embw_elems;
        hf     = outb + out_elems;
    } else {
        outb = ws;
        hf   = outb + out_elems;
    }

    if (use_embw) {
        embw_kernel<<<dim3(VV / 32, 2), 256, 0, stream>>>(
            emb, Wx_f, bi_f, Wx_b, bi_b, embW_f, embW_b);
        gru2_kernel<<<dim3(BB, 2), 64, 0, stream>>>(
            ids, embW_f, embW_b, Wh_f, br_f, Wh_b, br_b, outb, hf);
    } else {
        gru_kernel<false><<<dim3(BB / 4, 2), 192, 0, stream>>>(
            ids, embW_f, embW_b, emb, Wx_f, bi_f, Wx_b, bi_b,
            Wh_f, br_f, Wh_b, br_b, outb, hf);
    }
    attn2_kernel<<<BB, 256, 0, stream>>>(ids, outb, hf, Wk, bk, Wq, bq, We, be, ctx);
}

// Round 3
// 472.034 us; speedup vs baseline: 1.6067x; 1.2580x over previous
//
#include <hip/hip_runtime.h>
#include <hip/hip_bf16.h>

#define VV 100000
#define EE 50
#define HH 64
#define BB 1024
#define TT 200
// 3H = 192

__device__ __forceinline__ float fsig(float x) {
    return 1.f / (1.f + __expf(-x));
}
__device__ __forceinline__ float ftanh(float x) {
    float e = __expf(2.f * x);
    return 1.f - 2.f / (e + 1.f);
}

// ---------------- Kernel A: embW[v][c] = emb[v][:] @ Wx[:,c] + bi[c]  (both dirs via blockIdx.y) ----------------
__global__ __launch_bounds__(256) void embw_kernel(
    const float* __restrict__ emb,
    const float* __restrict__ Wx_f, const float* __restrict__ bi_f,
    const float* __restrict__ Wx_b, const float* __restrict__ bi_b,
    float* __restrict__ embW_f, float* __restrict__ embW_b)
{
    const float* Wx = blockIdx.y ? Wx_b : Wx_f;
    const float* bi = blockIdx.y ? bi_b : bi_f;
    float* embW     = blockIdx.y ? embW_b : embW_f;
    __shared__ float wx_lds[EE * 192];
    __shared__ float emb_lds[32 * EE];
    const int tid = threadIdx.x;
    const int v0 = blockIdx.x * 32;
    for (int i = tid; i < EE * 192; i += 256) wx_lds[i] = Wx[i];
    for (int i = tid; i < 32 * EE; i += 256) emb_lds[i] = emb[(size_t)v0 * EE + i];
    __syncthreads();
    const int cg = tid & 63;
    const int rg = tid >> 6;
    float acc[8][3];
    #pragma unroll
    for (int i = 0; i < 8; i++) {
        acc[i][0] = bi[cg];
        acc[i][1] = bi[cg + 64];
        acc[i][2] = bi[cg + 128];
    }
    for (int k = 0; k < EE; k++) {
        const float wx0 = wx_lds[k * 192 + cg];
        const float wx1 = wx_lds[k * 192 + cg + 64];
        const float wx2 = wx_lds[k * 192 + cg + 128];
        #pragma unroll
        for (int i = 0; i < 8; i++) {
            const float ev = emb_lds[(rg * 8 + i) * EE + k];
            acc[i][0] = fmaf(ev, wx0, acc[i][0]);
            acc[i][1] = fmaf(ev, wx1, acc[i][1]);
            acc[i][2] = fmaf(ev, wx2, acc[i][2]);
        }
    }
    #pragma unroll
    for (int i = 0; i < 8; i++) {
        const size_t row = (size_t)(v0 + rg * 8 + i) * 192;
        embW[row + cg]       = acc[i][0];
        embW[row + cg + 64]  = acc[i][1];
        embW[row + cg + 128] = acc[i][2];
    }
}

// ---------------- Kernel B v2: one wave per (sequence, direction); zero barriers in the step loop ----
__global__ __launch_bounds__(64, 2) void gru2_kernel(
    const int* __restrict__ ids,
    const float* __restrict__ embW_f, const float* __restrict__ embW_b,
    const float* __restrict__ Wh_f, const float* __restrict__ br_f,
    const float* __restrict__ Wh_b, const float* __restrict__ br_b,
    float* __restrict__ outb,     // [B, T, 128]
    float* __restrict__ hf_out)   // [B, 64]
{
    const int j   = threadIdx.x;
    const int b   = blockIdx.x;
    const int dir = blockIdx.y;
    const float* eW = dir ? embW_b : embW_f;
    const float* Wh = dir ? Wh_b : Wh_f;
    const float* br = dir ? br_b : br_f;

    float wz[64], wr[64], wn[64];
    #pragma unroll
    for (int k = 0; k < 64; k++) {
        wz[k] = Wh[k * 192 + j];
        wr[k] = Wh[k * 192 + 64 + j];
        wn[k] = Wh[k * 192 + 128 + j];
    }
    const float brz = br[j], brr = br[64 + j], brn = br[128 + j];

    __shared__ __align__(16) float h_lds[64];
    __shared__ int ids_lds[TT];
    for (int i = j; i < TT; i += 64) ids_lds[i] = ids[(size_t)b * TT + i];
    h_lds[j] = 0.f;
    float hj = 0.f;
    __syncthreads();   // one-time; none inside the step loop

    const int t0 = dir ? (TT - 1) : 0;
    const int dt = dir ? -1 : 1;

    int   id0 = ids_lds[t0];
    float gz0 = eW[(size_t)id0 * 192 + j];
    float gr0 = eW[(size_t)id0 * 192 + 64 + j];
    float gn0 = eW[(size_t)id0 * 192 + 128 + j];
    int   id1 = ids_lds[t0 + dt];
    float gz1 = eW[(size_t)id1 * 192 + j];
    float gr1 = eW[(size_t)id1 * 192 + 64 + j];
    float gn1 = eW[(size_t)id1 * 192 + 128 + j];

    float* obase = outb + (size_t)b * TT * 128 + dir * 64 + j;

    for (int s = 0; s < TT; s++) {
        const int t = t0 + s * dt;
        int id2 = 0; float gz2 = 0.f, gr2 = 0.f, gn2 = 0.f;
        if (s + 2 < TT) {
            id2 = ids_lds[t + 2 * dt];
            gz2 = eW[(size_t)id2 * 192 + j];
            gr2 = eW[(size_t)id2 * 192 + 64 + j];
            gn2 = eW[(size_t)id2 * 192 + 128 + j];
        }
        float az0 = brz, ar0 = brr, an0 = brn;
        float az1 = 0.f, ar1 = 0.f, an1 = 0.f;
        const float4* h4 = (const float4*)h_lds;
        #pragma unroll
        for (int k4 = 0; k4 < 16; k4++) {
            const float4 hv = h4[k4];
            az0 = fmaf(hv.x, wz[4 * k4 + 0], az0);
            ar0 = fmaf(hv.x, wr[4 * k4 + 0], ar0);
            an0 = fmaf(hv.x, wn[4 * k4 + 0], an0);
            az1 = fmaf(hv.y, wz[4 * k4 + 1], az1);
            ar1 = fmaf(hv.y, wr[4 * k4 + 1], ar1);
            an1 = fmaf(hv.y, wn[4 * k4 + 1], an1);
            az0 = fmaf(hv.z, wz[4 * k4 + 2], az0);
            ar0 = fmaf(hv.z, wr[4 * k4 + 2], ar0);
            an0 = fmaf(hv.z, wn[4 * k4 + 2], an0);
            az1 = fmaf(hv.w, wz[4 * k4 + 3], az1);
            ar1 = fmaf(hv.w, wr[4 * k4 + 3], ar1);
            an1 = fmaf(hv.w, wn[4 * k4 + 3], an1);
        }
        const float z  = fsig(gz0 + az0 + az1);
        const float r  = fsig(gr0 + ar0 + ar1);
        const float hh = ftanh(gn0 + r * (an0 + an1));
        float hnew = z * hj + (1.f - z) * hh;
        hnew = (id0 != 0) ? hnew : hj;
        hj = hnew;
        h_lds[j] = hj;
        obase[(size_t)t * 128] = hj;
        id0 = id1; gz0 = gz1; gr0 = gr1; gn0 = gn1;
        id1 = id2; gz1 = gz2; gr1 = gr2; gn1 = gn2;
    }
    if (dir == 0) hf_out[(size_t)b * 64 + j] = hj;
}

// ---------------- Kernel C v3: keys dot split across wave halves; 64 Wk regs/lane (no spill) ----------------
// Wave w: cg = w&1 -> columns [32*cg, 32*cg+32); tg = w>>1 -> t stripe (t ≡ tg mod 2).
// Lane: c = 32*cg + (lane&31); h = lane>>5 -> i-half [64h, 64h+64).
__global__ __launch_bounds__(256, 3) void attn3_kernel(
    const int* __restrict__ ids,
    const float* __restrict__ outb,   // [B,T,128]
    const float* __restrict__ hf,     // [B,64]
    const float* __restrict__ Wk, const float* __restrict__ bk,
    const float* __restrict__ Wq, const float* __restrict__ bq,
    const float* __restrict__ We, const float* __restrict__ be,
    float* __restrict__ ctx)          // [B,128]
{
    __shared__ float epart[2][TT];
    __shared__ float e_lds[TT];
    __shared__ float part[4][128];
    const int b = blockIdx.x;
    const int tid = threadIdx.x;
    const int w = tid >> 6;
    const int lane = tid & 63;
    const int cg = w & 1;
    const int tg = w >> 1;
    const int c = cg * 32 + (lane & 31);
    const int h = lane >> 5;

    // 64 Wk values per lane: rows [64h, 64h+64), column c
    float wkc[64];
    #pragma unroll
    for (int kk = 0; kk < 64; kk++) wkc[kk] = Wk[(size_t)(64 * h + kk) * 64 + c];

    // q'_c = bq[c] + bk[c] + hf[b] @ Wq[:,c]   (redundant per wave; no barrier)
    float qc = bq[c] + bk[c];
    {
        const float4* hf4 = (const float4*)(hf + (size_t)b * 64);
        #pragma unroll
        for (int k4 = 0; k4 < 16; k4++) {
            const float4 hv = hf4[k4];
            qc = fmaf(hv.x, Wq[(4 * k4 + 0) * 64 + c], qc);
            qc = fmaf(hv.y, Wq[(4 * k4 + 1) * 64 + c], qc);
            qc = fmaf(hv.z, Wq[(4 * k4 + 2) * 64 + c], qc);
            qc = fmaf(hv.w, Wq[(4 * k4 + 3) * 64 + c], qc);
        }
    }
    const float wec = We[c];
    const float bev = be[0];

    for (int t = tg; t < TT; t += 2) {
        const float4* o4 = (const float4*)(outb + ((size_t)b * TT + t) * 128 + 64 * h);
        float a0 = 0.f, a1 = 0.f;
        #pragma unroll
        for (int i4 = 0; i4 < 16; i4++) {
            const float4 ov = o4[i4];
            a0 = fmaf(ov.x, wkc[4 * i4 + 0], a0);
            a1 = fmaf(ov.y, wkc[4 * i4 + 1], a1);
            a0 = fmaf(ov.z, wkc[4 * i4 + 2], a0);
            a1 = fmaf(ov.w, wkc[4 * i4 + 3], a1);
        }
        float key = a0 + a1;
        key += __shfl_xor(key, 32);             // combine the two i-halves -> full 128-dot
        float v = ftanh(key + qc) * wec;        // per-column energy term
        #pragma unroll
        for (int off = 16; off > 0; off >>= 1)  // sum over the 32 columns of this group
            v += __shfl_xor(v, off);
        if (lane == 0) epart[cg][t] = v;
    }
    __syncthreads();
    if (w == 0) {
        for (int t = lane; t < TT; t += 64) {
            float e = epart[0][t] + epart[1][t] + bev;
            if (ids[(size_t)b * TT + t] == 0) e -= 1e9f;
            e_lds[t] = e;
        }
        float m = -1e30f;
        for (int t = lane; t < TT; t += 64) m = fmaxf(m, e_lds[t]);
        #pragma unroll
        for (int off = 32; off > 0; off >>= 1) m = fmaxf(m, __shfl_xor(m, off));
        float ssum = 0.f;
        for (int t = lane; t < TT; t += 64) { const float v = __expf(e_lds[t] - m); e_lds[t] = v; ssum += v; }
        #pragma unroll
        for (int off = 32; off > 0; off >>= 1) ssum += __shfl_xor(ssum, off);
        const float inv = 1.f / ssum;
        for (int t = lane; t < TT; t += 64) e_lds[t] *= inv;
    }
    __syncthreads();
    // context: wave w covers t ≡ w (mod 4); lanes cover 128 cols in two halves
    float c0 = 0.f, c1 = 0.f;
    for (int t = w; t < TT; t += 4) {
        const float* orow = outb + ((size_t)b * TT + t) * 128;
        const float wt = e_lds[t];
        c0 = fmaf(wt, orow[lane], c0);
        c1 = fmaf(wt, orow[64 + lane], c1);
    }
    part[w][lane] = c0;
    part[w][64 + lane] = c1;
    __syncthreads();
    if (tid < 128)
        ctx[(size_t)b * 128 + tid] = part[0][tid] + part[1][tid] + part[2][tid] + part[3][tid];
}

// ---------------- (fallback) GRU 3-wave kernel, recompute-gx variant ----------------
template<bool USE_EMBW>
__global__ __launch_bounds__(192) void gru_kernel(
    const int* __restrict__ ids,
    const float* __restrict__ embW_f, const float* __restrict__ embW_b,
    const float* __restrict__ emb,
    const float* __restrict__ Wx_f, const float* __restrict__ bi_f,
    const float* __restrict__ Wx_b, const float* __restrict__ bi_b,
    const float* __restrict__ Wh_f, const float* __restrict__ br_f,
    const float* __restrict__ Wh_b, const float* __restrict__ br_b,
    float* __restrict__ outb, float* __restrict__ hf_out)
{
    constexpr int R = 4;
    __shared__ float h_lds[R][64];
    __shared__ float rg_lds[R][64];
    __shared__ float hh_lds[R][64];
    __shared__ int ids_lds[R * TT];
    const int tid = threadIdx.x;
    const int w = tid >> 6;
    const int j = tid & 63;
    const int dir = blockIdx.y;
    const int b0 = blockIdx.x * R;
    const float* embW = dir ? embW_b : embW_f;
    const float* Wh   = dir ? Wh_b : Wh_f;
    const float* br   = dir ? br_b : br_f;
    const float* Wx   = dir ? Wx_b : Wx_f;
    const float* bi   = dir ? bi_b : bi_f;
    const int c = w * 64 + j;

    float whc[64];
    #pragma unroll
    for (int k = 0; k < 64; k++) whc[k] = Wh[k * 192 + c];
    const float brc = br[c];
    float wxc[EE];
    float bic = 0.f;
    if (!USE_EMBW) {
        #pragma unroll
        for (int k = 0; k < EE; k++) wxc[k] = Wx[k * 192 + c];
        bic = bi[c];
    }
    for (int i = tid; i < R * TT; i += 192) ids_lds[i] = ids[(size_t)b0 * TT + i];
    if (w == 0) {
        #pragma unroll
        for (int r = 0; r < R; r++) h_lds[r][j] = 0.f;
    }
    __syncthreads();

    for (int s = 0; s < TT; s++) {
        const int t = dir ? (TT - 1 - s) : s;
        int idv[R];
        float gxv[R], accv[R];
        #pragma unroll
        for (int r = 0; r < R; r++) idv[r] = ids_lds[r * TT + t];
        if (USE_EMBW) {
            #pragma unroll
            for (int r = 0; r < R; r++) gxv[r] = embW[(size_t)idv[r] * 192 + c];
        } else {
            #pragma unroll
            for (int r = 0; r < R; r++) {
                float acc = bic;
                const float* er = emb + (size_t)idv[r] * EE;
                #pragma unroll
                for (int k = 0; k < EE; k++) acc = fmaf(er[k], wxc[k], acc);
                gxv[r] = acc;
            }
        }
        #pragma unroll
        for (int r = 0; r < R; r++) {
            float acc = brc;
            const float4* h4 = (const float4*)(&h_lds[r][0]);
            #pragma unroll
            for (int k4 = 0; k4 < 16; k4++) {
                const float4 hv = h4[k4];
                acc = fmaf(hv.x, whc[4 * k4 + 0], acc);
                acc = fmaf(hv.y, whc[4 * k4 + 1], acc);
                acc = fmaf(hv.z, whc[4 * k4 + 2], acc);
                acc = fmaf(hv.w, whc[4 * k4 + 3], acc);
            }
            accv[r] = acc;
        }
        float zg[R] = {};
        if (w == 1) {
            #pragma unroll
            for (int r = 0; r < R; r++) rg_lds[r][j] = fsig(gxv[r] + accv[r]);
        } else if (w == 0) {
            #pragma unroll
            for (int r = 0; r < R; r++) zg[r] = fsig(gxv[r] + accv[r]);
        }
        __syncthreads();
        if (w == 2) {
            #pragma unroll
            for (int r = 0; r < R; r++)
                hh_lds[r][j] = ftanh(gxv[r] + rg_lds[r][j] * accv[r]);
        }
        __syncthreads();
        if (w == 0) {
            #pragma unroll
            for (int r = 0; r < R; r++) {
                const float hold = h_lds[r][j];
                float hnew = hold;
                if (idv[r] != 0) {
                    const float hh = hh_lds[r][j];
                    hnew = zg[r] * hold + (1.f - zg[r]) * hh;
                }
                h_lds[r][j] = hnew;
                outb[((size_t)(b0 + r) * TT + t) * 128 + dir * 64 + j] = hnew;
            }
        }
        __syncthreads();
    }
    if (dir == 0 && w == 0) {
        #pragma unroll
        for (int r = 0; r < R; r++) hf_out[(size_t)(b0 + r) * 64 + j] = h_lds[r][j];
    }
}

extern "C" void kernel_launch(void* const* d_in, const int* in_sizes, int n_in,
                              void* d_out, int out_size, void* d_ws, size_t ws_size,
                              hipStream_t stream) {
    const int*   ids  = (const int*)d_in[0];
    const float* emb  = (const float*)d_in[1];
    const float* Wx_f = (const float*)d_in[2];
    const float* Wh_f = (const float*)d_in[3];
    const float* bi_f = (const float*)d_in[4];
    const float* br_f = (const float*)d_in[5];
    const float* Wx_b = (const float*)d_in[6];
    const float* Wh_b = (const float*)d_in[7];
    const float* bi_b = (const float*)d_in[8];
    const float* br_b = (const float*)d_in[9];
    const float* Wk   = (const float*)d_in[10];
    const float* bk   = (const float*)d_in[11];
    const float* Wq   = (const float*)d_in[12];
    const float* bq   = (const float*)d_in[13];
    const float* We   = (const float*)d_in[14];
    const float* be   = (const float*)d_in[15];
    float* ctx = (float*)d_out;

    float* ws = (float*)d_ws;
    const size_t embw_elems = (size_t)VV * 192;
    const size_t out_elems  = (size_t)BB * TT * 128;
    const size_t hf_elems   = (size_t)BB * 64;
    const size_t need_embw  = (2 * embw_elems + out_elems + hf_elems) * sizeof(float);
    const bool use_embw = (ws_size >= need_embw);

    float *embW_f = nullptr, *embW_b = nullptr, *outb, *hf;
    if (use_embw) {
        embW_f = ws;
        embW_b = embW_f + embw_elems;
        outb   = embW_b + embw_elems;
        hf     = outb + out_elems;
    } else {
        outb = ws;
        hf   = outb + out_elems;
    }

    if (use_embw) {
        embw_kernel<<<dim3(VV / 32, 2), 256, 0, stream>>>(
            emb, Wx_f, bi_f, Wx_b, bi_b, embW_f, embW_b);
        gru2_kernel<<<dim3(BB, 2), 64, 0, stream>>>(
            ids, embW_f, embW_b, Wh_f, br_f, Wh_b, br_b, outb, hf);
    } else {
        gru_kernel<false><<<dim3(BB / 4, 2), 192, 0, stream>>>(
            ids, embW_f, embW_b, emb, Wx_f, bi_f, Wx_b, bi_b,
            Wh_f, br_f, Wh_b, br_b, outb, hf);
    }
    attn3_kernel<<<BB, 256, 0, stream>>>(ids, outb, hf, Wk, bk, Wq, bq, We, be, ctx);
}

// Round 4
// 463.070 us; speedup vs baseline: 1.6378x; 1.0194x over previous
//
#include <hip/hip_runtime.h>
#include <hip/hip_bf16.h>

#define VV 100000
#define EE 50
#define HH 64
#define BB 1024
#define TT 200
// 3H = 192

typedef float v4f __attribute__((ext_vector_type(4)));

__device__ __forceinline__ float fsig(float x) {
    return 1.f / (1.f + __expf(-x));
}
__device__ __forceinline__ float ftanh(float x) {
    float e = __expf(2.f * x);
    return 1.f - 2.f / (e + 1.f);
}

// ---------------- Kernel A: embW[v][c] = emb[v][:] @ Wx[:,c] + bi[c]  (both dirs via blockIdx.y) ----------------
__global__ __launch_bounds__(256) void embw_kernel(
    const float* __restrict__ emb,
    const float* __restrict__ Wx_f, const float* __restrict__ bi_f,
    const float* __restrict__ Wx_b, const float* __restrict__ bi_b,
    float* __restrict__ embW_f, float* __restrict__ embW_b)
{
    const float* Wx = blockIdx.y ? Wx_b : Wx_f;
    const float* bi = blockIdx.y ? bi_b : bi_f;
    float* embW     = blockIdx.y ? embW_b : embW_f;
    __shared__ float wx_lds[EE * 192];
    __shared__ float emb_lds[32 * EE];
    const int tid = threadIdx.x;
    const int v0 = blockIdx.x * 32;
    for (int i = tid; i < EE * 192; i += 256) wx_lds[i] = Wx[i];
    for (int i = tid; i < 32 * EE; i += 256) emb_lds[i] = emb[(size_t)v0 * EE + i];
    __syncthreads();
    const int cg = tid & 63;
    const int rg = tid >> 6;
    float acc[8][3];
    #pragma unroll
    for (int i = 0; i < 8; i++) {
        acc[i][0] = bi[cg];
        acc[i][1] = bi[cg + 64];
        acc[i][2] = bi[cg + 128];
    }
    for (int k = 0; k < EE; k++) {
        const float wx0 = wx_lds[k * 192 + cg];
        const float wx1 = wx_lds[k * 192 + cg + 64];
        const float wx2 = wx_lds[k * 192 + cg + 128];
        #pragma unroll
        for (int i = 0; i < 8; i++) {
            const float ev = emb_lds[(rg * 8 + i) * EE + k];
            acc[i][0] = fmaf(ev, wx0, acc[i][0]);
            acc[i][1] = fmaf(ev, wx1, acc[i][1]);
            acc[i][2] = fmaf(ev, wx2, acc[i][2]);
        }
    }
    #pragma unroll
    for (int i = 0; i < 8; i++) {
        const size_t row = (size_t)(v0 + rg * 8 + i) * 192;
        embW[row + cg]       = acc[i][0];
        embW[row + cg + 64]  = acc[i][1];
        embW[row + cg + 128] = acc[i][2];
    }
}

// ---------------- Kernel B v3: one wave per (sequence, direction); packed-fp32 FMA ----
// Lane j owns gate columns {j, 64+j, 128+j}; all 192 Wh weights in VGPRs as v4f.
// h broadcast via LDS b128 reads; 48 four-wide fma -> 96 v_pk_fma_f32 per step.
__global__ __launch_bounds__(64, 2) void gru3_kernel(
    const int* __restrict__ ids,
    const float* __restrict__ embW_f, const float* __restrict__ embW_b,
    const float* __restrict__ Wh_f, const float* __restrict__ br_f,
    const float* __restrict__ Wh_b, const float* __restrict__ br_b,
    float* __restrict__ outb,     // [B, T, 128]
    float* __restrict__ hf_out)   // [B, 64]
{
    const int j   = threadIdx.x;
    const int b   = blockIdx.x;
    const int dir = blockIdx.y;
    const float* eW = dir ? embW_b : embW_f;
    const float* Wh = dir ? Wh_b : Wh_f;
    const float* br = dir ? br_b : br_f;

    v4f wz4[16], wr4[16], wn4[16];
    #pragma unroll
    for (int k4 = 0; k4 < 16; k4++) {
        wz4[k4][0] = Wh[(4 * k4 + 0) * 192 + j];
        wz4[k4][1] = Wh[(4 * k4 + 1) * 192 + j];
        wz4[k4][2] = Wh[(4 * k4 + 2) * 192 + j];
        wz4[k4][3] = Wh[(4 * k4 + 3) * 192 + j];
        wr4[k4][0] = Wh[(4 * k4 + 0) * 192 + 64 + j];
        wr4[k4][1] = Wh[(4 * k4 + 1) * 192 + 64 + j];
        wr4[k4][2] = Wh[(4 * k4 + 2) * 192 + 64 + j];
        wr4[k4][3] = Wh[(4 * k4 + 3) * 192 + 64 + j];
        wn4[k4][0] = Wh[(4 * k4 + 0) * 192 + 128 + j];
        wn4[k4][1] = Wh[(4 * k4 + 1) * 192 + 128 + j];
        wn4[k4][2] = Wh[(4 * k4 + 2) * 192 + 128 + j];
        wn4[k4][3] = Wh[(4 * k4 + 3) * 192 + 128 + j];
    }
    const float brz = br[j], brr = br[64 + j], brn = br[128 + j];

    __shared__ __align__(16) float h_lds[64];
    __shared__ int ids_lds[TT];
    for (int i = j; i < TT; i += 64) ids_lds[i] = ids[(size_t)b * TT + i];
    h_lds[j] = 0.f;
    float hj = 0.f;
    __syncthreads();   // one-time; none inside the step loop

    const int t0 = dir ? (TT - 1) : 0;
    const int dt = dir ? -1 : 1;

    int   id0 = ids_lds[t0];
    float gz0 = eW[(size_t)id0 * 192 + j];
    float gr0 = eW[(size_t)id0 * 192 + 64 + j];
    float gn0 = eW[(size_t)id0 * 192 + 128 + j];
    int   id1 = ids_lds[t0 + dt];
    float gz1 = eW[(size_t)id1 * 192 + j];
    float gr1 = eW[(size_t)id1 * 192 + 64 + j];
    float gn1 = eW[(size_t)id1 * 192 + 128 + j];

    float* obase = outb + (size_t)b * TT * 128 + dir * 64 + j;

    for (int s = 0; s < TT; s++) {
        const int t = t0 + s * dt;
        int id2 = 0; float gz2 = 0.f, gr2 = 0.f, gn2 = 0.f;
        if (s + 2 < TT) {
            id2 = ids_lds[t + 2 * dt];
            gz2 = eW[(size_t)id2 * 192 + j];
            gr2 = eW[(size_t)id2 * 192 + 64 + j];
            gn2 = eW[(size_t)id2 * 192 + 128 + j];
        }
        v4f aZ = {brz, 0.f, 0.f, 0.f};
        v4f aR = {brr, 0.f, 0.f, 0.f};
        v4f aN = {brn, 0.f, 0.f, 0.f};
        const v4f* h4 = (const v4f*)h_lds;
        #pragma unroll
        for (int k4 = 0; k4 < 16; k4++) {
            const v4f hv = h4[k4];
            aZ = __builtin_elementwise_fma(hv, wz4[k4], aZ);
            aR = __builtin_elementwise_fma(hv, wr4[k4], aR);
            aN = __builtin_elementwise_fma(hv, wn4[k4], aN);
        }
        const float az = (aZ[0] + aZ[1]) + (aZ[2] + aZ[3]);
        const float ar = (aR[0] + aR[1]) + (aR[2] + aR[3]);
        const float an = (aN[0] + aN[1]) + (aN[2] + aN[3]);
        const float z  = fsig(gz0 + az);
        const float r  = fsig(gr0 + ar);
        const float hh = ftanh(gn0 + r * an);
        float hnew = z * hj + (1.f - z) * hh;
        hnew = (id0 != 0) ? hnew : hj;
        hj = hnew;
        h_lds[j] = hj;
        obase[(size_t)t * 128] = hj;
        id0 = id1; gz0 = gz1; gr0 = gr1; gn0 = gn1;
        id1 = id2; gz1 = gz2; gr1 = gr2; gn1 = gn2;
    }
    if (dir == 0) hf_out[(size_t)b * 64 + j] = hj;
}

// ---------------- Kernel C v4: attn3 with spill-proof bounds (256,2) + controlled unroll ----------------
// Wave w: cg = w&1 -> columns [32*cg, 32*cg+32); tg = w>>1 -> t stripe (t ≡ tg mod 2).
// Lane: c = 32*cg + (lane&31); h = lane>>5 -> i-half [64h, 64h+64).
__global__ __launch_bounds__(256, 2) void attn4_kernel(
    const int* __restrict__ ids,
    const float* __restrict__ outb,   // [B,T,128]
    const float* __restrict__ hf,     // [B,64]
    const float* __restrict__ Wk, const float* __restrict__ bk,
    const float* __restrict__ Wq, const float* __restrict__ bq,
    const float* __restrict__ We, const float* __restrict__ be,
    float* __restrict__ ctx)          // [B,128]
{
    __shared__ float epart[2][TT];
    __shared__ float e_lds[TT];
    __shared__ float part[4][128];
    const int b = blockIdx.x;
    const int tid = threadIdx.x;
    const int w = tid >> 6;
    const int lane = tid & 63;
    const int cg = w & 1;
    const int tg = w >> 1;
    const int c = cg * 32 + (lane & 31);
    const int h = lane >> 5;

    // 64 Wk values per lane: rows [64h, 64h+64), column c  (VGPR-resident: cap is 256 regs)
    float wkc[64];
    #pragma unroll
    for (int kk = 0; kk < 64; kk++) wkc[kk] = Wk[(size_t)(64 * h + kk) * 64 + c];

    // q'_c = bq[c] + bk[c] + hf[b] @ Wq[:,c]   (redundant per wave; no barrier)
    float qc = bq[c] + bk[c];
    {
        const float4* hf4 = (const float4*)(hf + (size_t)b * 64);
        #pragma unroll
        for (int k4 = 0; k4 < 16; k4++) {
            const float4 hv = hf4[k4];
            qc = fmaf(hv.x, Wq[(4 * k4 + 0) * 64 + c], qc);
            qc = fmaf(hv.y, Wq[(4 * k4 + 1) * 64 + c], qc);
            qc = fmaf(hv.z, Wq[(4 * k4 + 2) * 64 + c], qc);
            qc = fmaf(hv.w, Wq[(4 * k4 + 3) * 64 + c], qc);
        }
    }
    const float wec = We[c];
    const float bev = be[0];

    #pragma unroll 2
    for (int t = tg; t < TT; t += 2) {
        const float4* o4 = (const float4*)(outb + ((size_t)b * TT + t) * 128 + 64 * h);
        float a0 = 0.f, a1 = 0.f;
        #pragma unroll
        for (int i4 = 0; i4 < 16; i4++) {
            const float4 ov = o4[i4];
            a0 = fmaf(ov.x, wkc[4 * i4 + 0], a0);
            a1 = fmaf(ov.y, wkc[4 * i4 + 1], a1);
            a0 = fmaf(ov.z, wkc[4 * i4 + 2], a0);
            a1 = fmaf(ov.w, wkc[4 * i4 + 3], a1);
        }
        float key = a0 + a1;
        key += __shfl_xor(key, 32);             // combine the two i-halves -> full 128-dot
        float v = ftanh(key + qc) * wec;        // per-column energy term
        #pragma unroll
        for (int off = 16; off > 0; off >>= 1)  // sum over the 32 columns of this group
            v += __shfl_xor(v, off);
        if (lane == 0) epart[cg][t] = v;
    }
    __syncthreads();
    if (w == 0) {
        for (int t = lane; t < TT; t += 64) {
            float e = epart[0][t] + epart[1][t] + bev;
            if (ids[(size_t)b * TT + t] == 0) e -= 1e9f;
            e_lds[t] = e;
        }
        float m = -1e30f;
        for (int t = lane; t < TT; t += 64) m = fmaxf(m, e_lds[t]);
        #pragma unroll
        for (int off = 32; off > 0; off >>= 1) m = fmaxf(m, __shfl_xor(m, off));
        float ssum = 0.f;
        for (int t = lane; t < TT; t += 64) { const float v = __expf(e_lds[t] - m); e_lds[t] = v; ssum += v; }
        #pragma unroll
        for (int off = 32; off > 0; off >>= 1) ssum += __shfl_xor(ssum, off);
        const float inv = 1.f / ssum;
        for (int t = lane; t < TT; t += 64) e_lds[t] *= inv;
    }
    __syncthreads();
    // context: wave w covers t ≡ w (mod 4); lanes cover 128 cols in two halves
    float c0 = 0.f, c1 = 0.f;
    for (int t = w; t < TT; t += 4) {
        const float* orow = outb + ((size_t)b * TT + t) * 128;
        const float wt = e_lds[t];
        c0 = fmaf(wt, orow[lane], c0);
        c1 = fmaf(wt, orow[64 + lane], c1);
    }
    part[w][lane] = c0;
    part[w][64 + lane] = c1;
    __syncthreads();
    if (tid < 128)
        ctx[(size_t)b * 128 + tid] = part[0][tid] + part[1][tid] + part[2][tid] + part[3][tid];
}

// ---------------- (fallback) GRU 3-wave kernel, recompute-gx variant ----------------
template<bool USE_EMBW>
__global__ __launch_bounds__(192, 2) void gru_kernel(
    const int* __restrict__ ids,
    const float* __restrict__ embW_f, const float* __restrict__ embW_b,
    const float* __restrict__ emb,
    const float* __restrict__ Wx_f, const float* __restrict__ bi_f,
    const float* __restrict__ Wx_b, const float* __restrict__ bi_b,
    const float* __restrict__ Wh_f, const float* __restrict__ br_f,
    const float* __restrict__ Wh_b, const float* __restrict__ br_b,
    float* __restrict__ outb, float* __restrict__ hf_out)
{
    constexpr int R = 4;
    __shared__ float h_lds[R][64];
    __shared__ float rg_lds[R][64];
    __shared__ float hh_lds[R][64];
    __shared__ int ids_lds[R * TT];
    const int tid = threadIdx.x;
    const int w = tid >> 6;
    const int j = tid & 63;
    const int dir = blockIdx.y;
    const int b0 = blockIdx.x * R;
    const float* embW = dir ? embW_b : embW_f;
    const float* Wh   = dir ? Wh_b : Wh_f;
    const float* br   = dir ? br_b : br_f;
    const float* Wx   = dir ? Wx_b : Wx_f;
    const float* bi   = dir ? bi_b : bi_f;
    const int c = w * 64 + j;

    float whc[64];
    #pragma unroll
    for (int k = 0; k < 64; k++) whc[k] = Wh[k * 192 + c];
    const float brc = br[c];
    float wxc[EE];
    float bic = 0.f;
    if (!USE_EMBW) {
        #pragma unroll
        for (int k = 0; k < EE; k++) wxc[k] = Wx[k * 192 + c];
        bic = bi[c];
    }
    for (int i = tid; i < R * TT; i += 192) ids_lds[i] = ids[(size_t)b0 * TT + i];
    if (w == 0) {
        #pragma unroll
        for (int r = 0; r < R; r++) h_lds[r][j] = 0.f;
    }
    __syncthreads();

    for (int s = 0; s < TT; s++) {
        const int t = dir ? (TT - 1 - s) : s;
        int idv[R];
        float gxv[R], accv[R];
        #pragma unroll
        for (int r = 0; r < R; r++) idv[r] = ids_lds[r * TT + t];
        if (USE_EMBW) {
            #pragma unroll
            for (int r = 0; r < R; r++) gxv[r] = embW[(size_t)idv[r] * 192 + c];
        } else {
            #pragma unroll
            for (int r = 0; r < R; r++) {
                float acc = bic;
                const float* er = emb + (size_t)idv[r] * EE;
                #pragma unroll
                for (int k = 0; k < EE; k++) acc = fmaf(er[k], wxc[k], acc);
                gxv[r] = acc;
            }
        }
        #pragma unroll
        for (int r = 0; r < R; r++) {
            float acc = brc;
            const float4* h4 = (const float4*)(&h_lds[r][0]);
            #pragma unroll
            for (int k4 = 0; k4 < 16; k4++) {
                const float4 hv = h4[k4];
                acc = fmaf(hv.x, whc[4 * k4 + 0], acc);
                acc = fmaf(hv.y, whc[4 * k4 + 1], acc);
                acc = fmaf(hv.z, whc[4 * k4 + 2], acc);
                acc = fmaf(hv.w, whc[4 * k4 + 3], acc);
            }
            accv[r] = acc;
        }
        float zg[R] = {};
        if (w == 1) {
            #pragma unroll
            for (int r = 0; r < R; r++) rg_lds[r][j] = fsig(gxv[r] + accv[r]);
        } else if (w == 0) {
            #pragma unroll
            for (int r = 0; r < R; r++) zg[r] = fsig(gxv[r] + accv[r]);
        }
        __syncthreads();
        if (w == 2) {
            #pragma unroll
            for (int r = 0; r < R; r++)
                hh_lds[r][j] = ftanh(gxv[r] + rg_lds[r][j] * accv[r]);
        }
        __syncthreads();
        if (w == 0) {
            #pragma unroll
            for (int r = 0; r < R; r++) {
                const float hold = h_lds[r][j];
                float hnew = hold;
                if (idv[r] != 0) {
                    const float hh = hh_lds[r][j];
                    hnew = zg[r] * hold + (1.f - zg[r]) * hh;
                }
                h_lds[r][j] = hnew;
                outb[((size_t)(b0 + r) * TT + t) * 128 + dir * 64 + j] = hnew;
            }
        }
        __syncthreads();
    }
    if (dir == 0 && w == 0) {
        #pragma unroll
        for (int r = 0; r < R; r++) hf_out[(size_t)(b0 + r) * 64 + j] = h_lds[r][j];
    }
}

extern "C" void kernel_launch(void* const* d_in, const int* in_sizes, int n_in,
                              void* d_out, int out_size, void* d_ws, size_t ws_size,
                              hipStream_t stream) {
    const int*   ids  = (const int*)d_in[0];
    const float* emb  = (const float*)d_in[1];
    const float* Wx_f = (const float*)d_in[2];
    const float* Wh_f = (const float*)d_in[3];
    const float* bi_f = (const float*)d_in[4];
    const float* br_f = (const float*)d_in[5];
    const float* Wx_b = (const float*)d_in[6];
    const float* Wh_b = (const float*)d_in[7];
    const float* bi_b = (const float*)d_in[8];
    const float* br_b = (const float*)d_in[9];
    const float* Wk   = (const float*)d_in[10];
    const float* bk   = (const float*)d_in[11];
    const float* Wq   = (const float*)d_in[12];
    const float* bq   = (const float*)d_in[13];
    const float* We   = (const float*)d_in[14];
    const float* be   = (const float*)d_in[15];
    float* ctx = (float*)d_out;

    float* ws = (float*)d_ws;
    const size_t embw_elems = (size_t)VV * 192;
    const size_t out_elems  = (size_t)BB * TT * 128;
    const size_t hf_elems   = (size_t)BB * 64;
    const size_t need_embw  = (2 * embw_elems + out_elems + hf_elems) * sizeof(float);
    const bool use_embw = (ws_size >= need_embw);

    float *embW_f = nullptr, *embW_b = nullptr, *outb, *hf;
    if (use_embw) {
        embW_f = ws;
        embW_b = embW_f + embw_elems;
        outb   = embW_b + embw_elems;
        hf     = outb + out_elems;
    } else {
        outb = ws;
        hf   = outb + out_elems;
    }

    if (use_embw) {
        embw_kernel<<<dim3(VV / 32, 2), 256, 0, stream>>>(
            emb, Wx_f, bi_f, Wx_b, bi_b, embW_f, embW_b);
        gru3_kernel<<<dim3(BB, 2), 64, 0, stream>>>(
            ids, embW_f, embW_b, Wh_f, br_f, Wh_b, br_b, outb, hf);
    } else {
        gru_kernel<false><<<dim3(BB / 4, 2), 192, 0, stream>>>(
            ids, embW_f, embW_b, emb, Wx_f, bi_f, Wx_b, bi_b,
            Wh_f, br_f, Wh_b, br_b, outb, hf);
    }
    attn4_kernel<<<BB, 256, 0, stream>>>(ids, outb, hf, Wk, bk, Wq, bq, We, be, ctx);
}